// Round 1
// baseline (289.023 us; speedup 1.0000x reference)
//
#include <hip/hip_runtime.h>
#include <math.h>

// Problem constants (fixed by setup_inputs)
#define BATCH 8
#define CH    256
#define H     128
#define W     128
#define PLANE (H * W)            // 16384
#define NPIX  (BATCH * PLANE)    // 131072
#define NSHIFT 12                // symmetric half of the 24 shifts

// 12 "positive" shifts: dy>0 or (dy==0 && dx>0). Negatives are recovered by symmetry.
static __device__ __constant__ int S_DY[NSHIFT] = {0,0,1,1,1,1,1,2,2,2,2,2};
static __device__ __constant__ int S_DX[NSHIFT] = {1,2,-2,-1,0,1,2,-2,-1,0,1,2};

// ---------------------------------------------------------------------------
// Kernel 0: per-image stats — cnt[b] (# valid interior boundary px), inc[b]
// ---------------------------------------------------------------------------
__global__ void k_stats(const int* __restrict__ seg, const int* __restrict__ gtb,
                        int* __restrict__ cnt, int* __restrict__ inc) {
    int b = blockIdx.x;
    int t = threadIdx.x;
    int my_cnt = 0, my_any = 0;
    for (int i = t; i < PLANE; i += 256) {
        int s = seg[b * PLANE + i];
        int g = gtb[b * PLANE + i];
        int s0 = (s == 255) ? 0 : s;
        int g0 = (g == 255) ? 0 : g;
        if (s0 > 0 && g0 > 0) {
            my_any = 1;
            int y = i >> 7, x = i & 127;
            if (y >= 2 && y < H - 2 && x >= 2 && x < W - 2) my_cnt++;
        }
    }
    __shared__ int sc[256], sa[256];
    sc[t] = my_cnt; sa[t] = my_any;
    __syncthreads();
    for (int o = 128; o > 0; o >>= 1) {
        if (t < o) { sc[t] += sc[t + o]; sa[t] |= sa[t + o]; }
        __syncthreads();
    }
    if (t == 0) { cnt[b] = sc[0]; inc[b] = sa[0]; }
}

// ---------------------------------------------------------------------------
// Kernel 0b: scalar factors per image + zero the output accumulator
// factor[b] = include_b ? 1/(24 * max(cnt_b,1) * scale_num) : 0
// ---------------------------------------------------------------------------
__global__ void k_factor(const int* __restrict__ cnt, const int* __restrict__ inc,
                         float* __restrict__ factor, float* __restrict__ out) {
    if (blockIdx.x == 0 && threadIdx.x == 0) {
        int sn = 0;
        for (int b = 0; b < BATCH; b++) sn += inc[b];
        if (sn < 1) sn = 1;
        for (int b = 0; b < BATCH; b++) {
            int c = cnt[b] < 1 ? 1 : cnt[b];
            factor[b] = inc[b] ? 1.0f / (24.0f * (float)c * (float)sn) : 0.0f;
        }
        out[0] = 0.0f;
    }
}

// ---------------------------------------------------------------------------
// Kernel 2: shifted-correlation maps + norms.
// Block: 256 thr = 2 output rows x 128 px. Stages 4 rows x 4 channels as
// float4-per-pixel in LDS (transpose), accumulates sumsq + 12 shifted dots.
// ---------------------------------------------------------------------------
// 13 read positions: index 0 = (0,0) for sumsq; 1..12 = S_DY/S_DX shifts.
static __device__ __constant__ int P_DY[13] = {0,0,0,1,1,1,1,1,2,2,2,2,2};
static __device__ __constant__ int P_DX[13] = {0,1,2,-2,-1,0,1,2,-2,-1,0,1,2};

__global__ __launch_bounds__(256) void k_corr(const float* __restrict__ er,
                                              float* __restrict__ dots,
                                              float* __restrict__ norms) {
    __shared__ float4 lds[4][132];   // 4 staged rows, x padded by 2 each side
    int blk = blockIdx.x;
    int b = blk >> 6;                // 64 row-tiles per image
    int tile = blk & 63;
    int y0 = tile * 2;
    int t = threadIdx.x;
    int r = t >> 7;                  // local output row 0..1
    int x = t & 127;

    // zero the x-pad slots once (never overwritten by staging)
    if (t < 16) {
        int row = t >> 2, col = t & 3;
        int xs = (col < 2) ? col : (col + 128);   // 0,1,130,131
        lds[row][xs] = make_float4(0.f, 0.f, 0.f, 0.f);
    }

    float acc[13];
#pragma unroll
    for (int i = 0; i < 13; i++) acc[i] = 0.0f;

    const float* base = er + (size_t)b * CH * PLANE;

    for (int c = 0; c < CH; c += 4) {
        __syncthreads();   // prior reads done (also makes pad-zero visible)
        // stage 4 rows x 128 px x 4 channels -> float4 per pixel
#pragma unroll
        for (int k = 0; k < 2; ++k) {
            int s = t + k * 256;         // 0..511
            int row = s >> 7;            // 0..3
            int xs = s & 127;
            int y = y0 + row;
            float4 v = make_float4(0.f, 0.f, 0.f, 0.f);
            if (y < H) {
                const float* p0 = base + (size_t)c * PLANE + y * W + xs;
                v.x = p0[0];
                v.y = p0[PLANE];
                v.z = p0[2 * PLANE];
                v.w = p0[3 * PLANE];
            }
            lds[row][xs + 2] = v;
        }
        __syncthreads();

        const float4* lp = &lds[r][x + 2];
        float4 cen = lp[0];
#pragma unroll
        for (int i = 0; i < 13; ++i) {
            float4 v = lp[P_DY[i] * 132 + P_DX[i]];
            acc[i] = fmaf(cen.x, v.x, acc[i]);
            acc[i] = fmaf(cen.y, v.y, acc[i]);
            acc[i] = fmaf(cen.z, v.z, acc[i]);
            acc[i] = fmaf(cen.w, v.w, acc[i]);
        }
    }

    int y = y0 + r;                       // always < H (y0 <= 126)
    int pix = b * PLANE + y * W + x;
    norms[pix] = fmaxf(sqrtf(acc[0]), 1e-8f);
#pragma unroll
    for (int i = 0; i < NSHIFT; ++i)
        dots[i * NPIX + pix] = acc[i + 1];
}

// ---------------------------------------------------------------------------
// Kernel 3: per-valid-pixel loss assembly + reduction into out[0]
// ---------------------------------------------------------------------------
__global__ __launch_bounds__(256) void k_loss(const float* __restrict__ dots,
                                              const float* __restrict__ norms,
                                              const int* __restrict__ seg,
                                              const int* __restrict__ gtb,
                                              const float* __restrict__ factor,
                                              float* __restrict__ out) {
    int idx = blockIdx.x * 256 + threadIdx.x;
    int b = idx >> 14;
    int rem = idx & (PLANE - 1);
    int y = rem >> 7;
    int x = rem & 127;

    float val = 0.0f;
    if (y >= 2 && y < H - 2 && x >= 2 && x < W - 2) {
        int sp = seg[idx];
        int gp = gtb[idx];
        int s0 = (sp == 255) ? 0 : sp;
        int g0 = (gp == 255) ? 0 : gp;
        if (s0 > 0 && g0 > 0) {
            float np = norms[idx];
            float sum = 0.0f;
#pragma unroll
            for (int i = 0; i < NSHIFT; ++i) {
                int off = S_DY[i] * W + S_DX[i];
                // + shift: cos(p, p+d)
                {
                    float d  = dots[i * NPIX + idx];
                    float nn = norms[idx + off];
                    float cosv = d / (np * nn);
                    int sq = seg[idx + off];
                    float lab = (sp == sq && sp < 2) ? 1.0f : 0.0f;
                    float tt = cosv - lab;
                    sum = fmaf(tt, tt, sum);
                }
                // - shift: cos(p, p-d) = dot_d(p-d)/(norm(p)norm(p-d))
                {
                    float d  = dots[i * NPIX + idx - off];
                    float nn = norms[idx - off];
                    float cosv = d / (np * nn);
                    int sq = seg[idx - off];
                    float lab = (sp == sq && sp < 2) ? 1.0f : 0.0f;
                    float tt = cosv - lab;
                    sum = fmaf(tt, tt, sum);
                }
            }
            val = sum * factor[b];
        }
    }

    // block reduction: wave shuffle then LDS across 4 waves
    for (int o = 32; o > 0; o >>= 1)
        val += __shfl_down(val, o, 64);
    __shared__ float wsum[4];
    int lane = threadIdx.x & 63;
    int wid  = threadIdx.x >> 6;
    if (lane == 0) wsum[wid] = val;
    __syncthreads();
    if (threadIdx.x == 0) {
        float s = wsum[0] + wsum[1] + wsum[2] + wsum[3];
        atomicAdd(out, s);
    }
}

// ---------------------------------------------------------------------------
extern "C" void kernel_launch(void* const* d_in, const int* in_sizes, int n_in,
                              void* d_out, int out_size, void* d_ws, size_t ws_size,
                              hipStream_t stream) {
    const float* er  = (const float*)d_in[0];
    const int*   seg = (const int*)d_in[1];
    const int*   gtb = (const int*)d_in[2];
    float* out = (float*)d_out;

    float* ws     = (float*)d_ws;
    float* dots   = ws;                      // 12 * NPIX floats (6.3 MB)
    float* norms  = dots + NSHIFT * NPIX;    // NPIX floats (512 KB)
    float* factor = norms + NPIX;            // 8 floats
    int*   cnt    = (int*)(factor + 8);      // 8 ints
    int*   inc    = cnt + 8;                 // 8 ints

    hipLaunchKernelGGL(k_stats,  dim3(BATCH), dim3(256), 0, stream, seg, gtb, cnt, inc);
    hipLaunchKernelGGL(k_factor, dim3(1),     dim3(64),  0, stream, cnt, inc, factor, out);
    hipLaunchKernelGGL(k_corr,   dim3(BATCH * (H / 2)), dim3(256), 0, stream, er, dots, norms);
    hipLaunchKernelGGL(k_loss,   dim3(NPIX / 256), dim3(256), 0, stream,
                       dots, norms, seg, gtb, factor, out);
}

// Round 2
// 235.174 us; speedup vs baseline: 1.2290x; 1.2290x over previous
//
#include <hip/hip_runtime.h>
#include <math.h>

// Problem constants (fixed by setup_inputs)
#define BATCH 8
#define CH    256
#define H     128
#define W     128
#define PLANE (H * W)            // 16384
#define NPIX  (BATCH * PLANE)    // 131072
#define NSHIFT 12                // symmetric half of the 24 shifts
#define NCHUNK 4                 // channel chunks (occupancy: 2048 blocks -> 32 waves/CU)
#define CPC    (CH / NCHUNK)     // channels per chunk = 64

// 12 "positive" shifts: dy>0 or (dy==0 && dx>0). Negatives recovered by symmetry.
static __device__ __constant__ int S_DY[NSHIFT] = {0,0,1,1,1,1,1,2,2,2,2,2};
static __device__ __constant__ int S_DX[NSHIFT] = {1,2,-2,-1,0,1,2,-2,-1,0,1,2};

// 13 read positions: index 0 = (0,0) for sumsq; 1..12 = S_DY/S_DX shifts.
static __device__ __constant__ int P_DY[13] = {0,0,0,1,1,1,1,1,2,2,2,2,2};
static __device__ __constant__ int P_DX[13] = {0,1,2,-2,-1,0,1,2,-2,-1,0,1,2};

// Zero-fill region: dots(12*NPIX) + normsq(NPIX) + factor(8) + cnt(8) + inc(8) + pad
#define NZERO4 ((13 * NPIX + 32) / 4)   // float4 count (16B aligned, exact)

// ---------------------------------------------------------------------------
// Kernel Z: zero the accumulator region of d_ws (harness poisons it to 0xAA)
// ---------------------------------------------------------------------------
__global__ __launch_bounds__(256) void k_zero(float4* __restrict__ p) {
    int i = blockIdx.x * 256 + threadIdx.x;
    if (i < NZERO4) p[i] = make_float4(0.f, 0.f, 0.f, 0.f);
}

// ---------------------------------------------------------------------------
// Kernel 0: per-image stats — cnt[b] (# valid interior boundary px), inc[b]
// 512 blocks (64 per image), block-reduce, one atomic per block.
// ---------------------------------------------------------------------------
__global__ __launch_bounds__(256) void k_stats(const int* __restrict__ seg,
                                               const int* __restrict__ gtb,
                                               int* __restrict__ cnt,
                                               int* __restrict__ inc) {
    int b = blockIdx.x >> 6;
    int i = (blockIdx.x & 63) * 256 + threadIdx.x;   // pixel in plane
    int my_cnt = 0, my_any = 0;
    {
        int s = seg[b * PLANE + i];
        int g = gtb[b * PLANE + i];
        int s0 = (s == 255) ? 0 : s;
        int g0 = (g == 255) ? 0 : g;
        if (s0 > 0 && g0 > 0) {
            my_any = 1;
            int y = i >> 7, x = i & 127;
            if (y >= 2 && y < H - 2 && x >= 2 && x < W - 2) my_cnt = 1;
        }
    }
    // wave reduce
    for (int o = 32; o > 0; o >>= 1) {
        my_cnt += __shfl_down(my_cnt, o, 64);
        my_any |= __shfl_down(my_any, o, 64);
    }
    __shared__ int sc[4], sa[4];
    int lane = threadIdx.x & 63, wid = threadIdx.x >> 6;
    if (lane == 0) { sc[wid] = my_cnt; sa[wid] = my_any; }
    __syncthreads();
    if (threadIdx.x == 0) {
        int c = sc[0] + sc[1] + sc[2] + sc[3];
        int a = sa[0] | sa[1] | sa[2] | sa[3];
        if (c) atomicAdd(&cnt[b], c);
        if (a) atomicOr(&inc[b], 1);
    }
}

// ---------------------------------------------------------------------------
// Kernel 0b: scalar factors per image + zero the output accumulator
// ---------------------------------------------------------------------------
__global__ void k_factor(const int* __restrict__ cnt, const int* __restrict__ inc,
                         float* __restrict__ factor, float* __restrict__ out) {
    if (blockIdx.x == 0 && threadIdx.x == 0) {
        int sn = 0;
        for (int b = 0; b < BATCH; b++) sn += (inc[b] != 0);
        if (sn < 1) sn = 1;
        for (int b = 0; b < BATCH; b++) {
            int c = cnt[b] < 1 ? 1 : cnt[b];
            factor[b] = inc[b] ? 1.0f / (24.0f * (float)c * (float)sn) : 0.0f;
        }
        out[0] = 0.0f;
    }
}

// ---------------------------------------------------------------------------
// Kernel 2: shifted-correlation maps + sum-of-squares (norm^2).
// Grid 2048 = 8 images x 64 row-tiles x 4 channel-chunks; 256 thr = 2 rows x 128 px.
// Stages 4 rows x 4 channels as float4-per-pixel in LDS; accumulates 13 dots
// over the chunk's 64 channels; atomicAdd into global accumulators.
// ---------------------------------------------------------------------------
__global__ __launch_bounds__(256) void k_corr(const float* __restrict__ er,
                                              float* __restrict__ dots,
                                              float* __restrict__ normsq) {
    __shared__ float4 lds[4][132];   // 4 staged rows, x padded by 2 each side
    int blk = blockIdx.x;
    int chunk = blk & 3;
    int tile  = (blk >> 2) & 63;
    int b     = blk >> 8;
    int y0 = tile * 2;
    int c0 = chunk * CPC;
    int t = threadIdx.x;
    int r = t >> 7;                  // local output row 0..1
    int x = t & 127;

    // zero the x-pad slots once (never overwritten by staging)
    if (t < 16) {
        int row = t >> 2, col = t & 3;
        int xs = (col < 2) ? col : (col + 128);   // 0,1,130,131
        lds[row][xs] = make_float4(0.f, 0.f, 0.f, 0.f);
    }

    float acc[13];
#pragma unroll
    for (int i = 0; i < 13; i++) acc[i] = 0.0f;

    const float* base = er + (size_t)b * CH * PLANE;

    for (int c = c0; c < c0 + CPC; c += 4) {
        __syncthreads();   // prior reads done (also makes pad-zero visible)
        // stage 4 rows x 128 px x 4 channels -> float4 per pixel (transposed)
#pragma unroll
        for (int k = 0; k < 2; ++k) {
            int s = t + k * 256;         // 0..511
            int row = s >> 7;            // 0..3
            int xs = s & 127;
            int y = y0 + row;
            float4 v = make_float4(0.f, 0.f, 0.f, 0.f);
            if (y < H) {
                const float* p0 = base + (size_t)c * PLANE + y * W + xs;
                v.x = p0[0];
                v.y = p0[PLANE];
                v.z = p0[2 * PLANE];
                v.w = p0[3 * PLANE];
            }
            lds[row][xs + 2] = v;
        }
        __syncthreads();

        const float4* lp = &lds[r][x + 2];
        float4 cen = lp[0];
#pragma unroll
        for (int i = 0; i < 13; ++i) {
            float4 v = lp[P_DY[i] * 132 + P_DX[i]];
            acc[i] = fmaf(cen.x, v.x, acc[i]);
            acc[i] = fmaf(cen.y, v.y, acc[i]);
            acc[i] = fmaf(cen.z, v.z, acc[i]);
            acc[i] = fmaf(cen.w, v.w, acc[i]);
        }
    }

    int y = y0 + r;                       // always < H (y0 <= 126)
    int pix = b * PLANE + y * W + x;
    atomicAdd(&normsq[pix], acc[0]);
#pragma unroll
    for (int i = 0; i < NSHIFT; ++i)
        atomicAdd(&dots[i * NPIX + pix], acc[i + 1]);
}

// ---------------------------------------------------------------------------
// Kernel 3: per-valid-pixel loss assembly + reduction into out[0]
// ---------------------------------------------------------------------------
__global__ __launch_bounds__(256) void k_loss(const float* __restrict__ dots,
                                              const float* __restrict__ normsq,
                                              const int* __restrict__ seg,
                                              const int* __restrict__ gtb,
                                              const float* __restrict__ factor,
                                              float* __restrict__ out) {
    int idx = blockIdx.x * 256 + threadIdx.x;
    int b = idx >> 14;
    int rem = idx & (PLANE - 1);
    int y = rem >> 7;
    int x = rem & 127;

    float val = 0.0f;
    if (y >= 2 && y < H - 2 && x >= 2 && x < W - 2) {
        int sp = seg[idx];
        int gp = gtb[idx];
        int s0 = (sp == 255) ? 0 : sp;
        int g0 = (gp == 255) ? 0 : gp;
        if (s0 > 0 && g0 > 0) {
            float np = fmaxf(sqrtf(normsq[idx]), 1e-8f);
            float sum = 0.0f;
#pragma unroll
            for (int i = 0; i < NSHIFT; ++i) {
                int off = S_DY[i] * W + S_DX[i];
                // + shift: cos(p, p+d)
                {
                    float d  = dots[i * NPIX + idx];
                    float nn = fmaxf(sqrtf(normsq[idx + off]), 1e-8f);
                    float cosv = d / (np * nn);
                    int sq = seg[idx + off];
                    float lab = (sp == sq && sp < 2) ? 1.0f : 0.0f;
                    float tt = cosv - lab;
                    sum = fmaf(tt, tt, sum);
                }
                // - shift: cos(p, p-d) = dot_d(p-d)/(norm(p)norm(p-d))
                {
                    float d  = dots[i * NPIX + idx - off];
                    float nn = fmaxf(sqrtf(normsq[idx - off]), 1e-8f);
                    float cosv = d / (np * nn);
                    int sq = seg[idx - off];
                    float lab = (sp == sq && sp < 2) ? 1.0f : 0.0f;
                    float tt = cosv - lab;
                    sum = fmaf(tt, tt, sum);
                }
            }
            val = sum * factor[b];
        }
    }

    // block reduction: wave shuffle then LDS across 4 waves
    for (int o = 32; o > 0; o >>= 1)
        val += __shfl_down(val, o, 64);
    __shared__ float wsum[4];
    int lane = threadIdx.x & 63;
    int wid  = threadIdx.x >> 6;
    if (lane == 0) wsum[wid] = val;
    __syncthreads();
    if (threadIdx.x == 0) {
        float s = wsum[0] + wsum[1] + wsum[2] + wsum[3];
        atomicAdd(out, s);
    }
}

// ---------------------------------------------------------------------------
extern "C" void kernel_launch(void* const* d_in, const int* in_sizes, int n_in,
                              void* d_out, int out_size, void* d_ws, size_t ws_size,
                              hipStream_t stream) {
    const float* er  = (const float*)d_in[0];
    const int*   seg = (const int*)d_in[1];
    const int*   gtb = (const int*)d_in[2];
    float* out = (float*)d_out;

    float* ws     = (float*)d_ws;
    float* dots   = ws;                      // 12 * NPIX floats (6.3 MB)
    float* normsq = dots + NSHIFT * NPIX;    // NPIX floats (512 KB)
    float* factor = normsq + NPIX;           // 8 floats
    int*   cnt    = (int*)(factor + 8);      // 8 ints
    int*   inc    = cnt + 8;                 // 8 ints

    hipLaunchKernelGGL(k_zero,   dim3((NZERO4 + 255) / 256), dim3(256), 0, stream,
                       (float4*)d_ws);
    hipLaunchKernelGGL(k_stats,  dim3(BATCH * 64), dim3(256), 0, stream, seg, gtb, cnt, inc);
    hipLaunchKernelGGL(k_factor, dim3(1), dim3(64), 0, stream, cnt, inc, factor, out);
    hipLaunchKernelGGL(k_corr,   dim3(BATCH * 64 * NCHUNK), dim3(256), 0, stream,
                       er, dots, normsq);
    hipLaunchKernelGGL(k_loss,   dim3(NPIX / 256), dim3(256), 0, stream,
                       dots, normsq, seg, gtb, factor, out);
}

// Round 3
// 230.378 us; speedup vs baseline: 1.2546x; 1.0208x over previous
//
#include <hip/hip_runtime.h>
#include <math.h>

// Problem constants (fixed by setup_inputs)
#define BATCH 8
#define CH    256
#define H     128
#define W     128
#define PLANE (H * W)            // 16384
#define NPIX  (BATCH * PLANE)    // 131072
#define NSHIFT 12                // symmetric half of the 24 shifts
#define NCHUNK 4                 // channel chunks (occupancy)
#define CPC    (CH / NCHUNK)     // channels per chunk = 64

// 12 "positive" shifts: dy>0 or (dy==0 && dx>0). Negatives recovered by symmetry.
// order: i=0..1 -> (0,1),(0,2); i=2..6 -> (1,-2..2); i=7..11 -> (2,-2..2)
static __device__ __constant__ int S_DY[NSHIFT] = {0,0,1,1,1,1,1,2,2,2,2,2};
static __device__ __constant__ int S_DX[NSHIFT] = {1,2,-2,-1,0,1,2,-2,-1,0,1,2};

// Zero region: dots(12*NPIX) + normsq(NPIX) + cnt(8) + inc(8)  [floats/ints]
#define NZERO4 ((13 * NPIX + 16) / 4)            // exact float4 count
#define NZB    ((NZERO4 + 255) / 256)            // zero blocks

#define NCORRB (BATCH * 32 * NCHUNK)             // 1024 corr blocks
#define NSTATB (BATCH * 64)                      // 512 stats blocks

__device__ __forceinline__ void fma4(float& acc, const float4& a, const float4& b) {
    acc = fmaf(a.x, b.x, acc);
    acc = fmaf(a.y, b.y, acc);
    acc = fmaf(a.z, b.z, acc);
    acc = fmaf(a.w, b.w, acc);
}

// ---------------------------------------------------------------------------
// Kernel P: zero accumulator region of d_ws + out[0]
// ---------------------------------------------------------------------------
__global__ __launch_bounds__(256) void k_prep(float4* __restrict__ p,
                                              float* __restrict__ out) {
    int i = blockIdx.x * 256 + threadIdx.x;
    if (i < NZERO4) p[i] = make_float4(0.f, 0.f, 0.f, 0.f);
    if (i == 0) out[0] = 0.0f;
}

// ---------------------------------------------------------------------------
// Kernel C: fused correlation + per-image stats.
// Blocks [0, NCORRB): shifted-correlation maps + sum-of-squares.
//   Grid decode: chunk | tile(32) | b.  256 thr; each thread computes 2
//   adjacent output rows (block covers 4 rows, stages 6 rows x 4 channels as
//   float4-per-pixel in LDS).  atomicAdd into global accumulators.
// Blocks [NCORRB, NCORRB+NSTATB): per-image cnt/inc stats.
// ---------------------------------------------------------------------------
__global__ __launch_bounds__(256) void k_corr(const float* __restrict__ er,
                                              const int* __restrict__ seg,
                                              const int* __restrict__ gtb,
                                              float* __restrict__ dots,
                                              float* __restrict__ normsq,
                                              int* __restrict__ cnt,
                                              int* __restrict__ inc) {
    __shared__ float4 lds[6][132];   // 6 staged rows, x padded by 2 each side
    int t = threadIdx.x;

    if (blockIdx.x >= NCORRB) {
        // ---- stats path ----
        int blk2 = blockIdx.x - NCORRB;
        int b = blk2 >> 6;
        int i = (blk2 & 63) * 256 + t;
        int my_cnt = 0, my_any = 0;
        {
            int s = seg[b * PLANE + i];
            int g = gtb[b * PLANE + i];
            int s0 = (s == 255) ? 0 : s;
            int g0 = (g == 255) ? 0 : g;
            if (s0 > 0 && g0 > 0) {
                my_any = 1;
                int y = i >> 7, x = i & 127;
                if (y >= 2 && y < H - 2 && x >= 2 && x < W - 2) my_cnt = 1;
            }
        }
        for (int o = 32; o > 0; o >>= 1) {
            my_cnt += __shfl_down(my_cnt, o, 64);
            my_any |= __shfl_down(my_any, o, 64);
        }
        __shared__ int sc[4], sa[4];
        int lane = t & 63, wid = t >> 6;
        if (lane == 0) { sc[wid] = my_cnt; sa[wid] = my_any; }
        __syncthreads();
        if (t == 0) {
            int c = sc[0] + sc[1] + sc[2] + sc[3];
            int a = sa[0] | sa[1] | sa[2] | sa[3];
            if (c) atomicAdd(&cnt[b], c);
            if (a) atomicOr(&inc[b], 1);
        }
        return;
    }

    // ---- correlation path ----
    int blk = blockIdx.x;
    int chunk = blk & 3;
    int tile  = (blk >> 2) & 31;
    int b     = blk >> 7;
    int y0 = tile * 4;               // block covers output rows y0..y0+3
    int c0 = chunk * CPC;
    int r = t >> 7;                  // thread handles output rows y0+2r, y0+2r+1
    int x = t & 127;

    // zero the x-pad slots once (never overwritten by staging)
    if (t < 24) {
        int row = t >> 2, col = t & 3;
        int xs = (col < 2) ? col : (col + 128);   // 0,1,130,131
        lds[row][xs] = make_float4(0.f, 0.f, 0.f, 0.f);
    }

    float accA[13], accB[13];
#pragma unroll
    for (int i = 0; i < 13; i++) { accA[i] = 0.0f; accB[i] = 0.0f; }

    const float* base = er + (size_t)b * CH * PLANE;

    for (int c = c0; c < c0 + CPC; c += 4) {
        __syncthreads();   // prior reads done (also makes pad-zero visible)
        // stage 6 rows x 128 px x 4 channels -> float4 per pixel (transposed)
#pragma unroll
        for (int k = 0; k < 3; ++k) {
            int s = t + k * 256;         // 0..767
            int row = s >> 7;            // 0..5
            int xs = s & 127;
            int y = y0 + row;
            float4 v = make_float4(0.f, 0.f, 0.f, 0.f);
            if (y < H) {
                const float* p0 = base + (size_t)c * PLANE + y * W + xs;
                v.x = p0[0];
                v.y = p0[PLANE];
                v.z = p0[2 * PLANE];
                v.w = p0[3 * PLANE];
            }
            lds[row][xs + 2] = v;
        }
        __syncthreads();

        const float4* lp = &lds[2 * r][x + 2];
        float4 cA = lp[0];               // (rel row 0, dx 0)
        float4 cB = lp[132];             // (rel row 1, dx 0)
        // rel row 0: dx {0,1,2} -> accA[0..2]
        {
            float4 v1 = lp[1], v2 = lp[2];
            fma4(accA[0], cA, cA);
            fma4(accA[1], cA, v1);
            fma4(accA[2], cA, v2);
        }
        // rel row 1: dx {-2..2} -> accA[3..7]; accB[0..2] (dx 0,1,2)
        {
            float4 m2 = lp[130], m1 = lp[131], p1 = lp[133], p2 = lp[134];
            fma4(accA[3], cA, m2);
            fma4(accA[4], cA, m1);
            fma4(accA[5], cA, cB);
            fma4(accA[6], cA, p1);
            fma4(accA[7], cA, p2);
            fma4(accB[0], cB, cB);
            fma4(accB[1], cB, p1);
            fma4(accB[2], cB, p2);
        }
        // rel row 2: dx {-2..2} -> accA[8..12]; accB[3..7]
        {
            float4 m2 = lp[262], m1 = lp[263], v0 = lp[264], p1 = lp[265], p2 = lp[266];
            fma4(accA[8],  cA, m2);
            fma4(accA[9],  cA, m1);
            fma4(accA[10], cA, v0);
            fma4(accA[11], cA, p1);
            fma4(accA[12], cA, p2);
            fma4(accB[3], cB, m2);
            fma4(accB[4], cB, m1);
            fma4(accB[5], cB, v0);
            fma4(accB[6], cB, p1);
            fma4(accB[7], cB, p2);
        }
        // rel row 3: dx {-2..2} -> accB[8..12]
        {
            float4 m2 = lp[394], m1 = lp[395], v0 = lp[396], p1 = lp[397], p2 = lp[398];
            fma4(accB[8],  cB, m2);
            fma4(accB[9],  cB, m1);
            fma4(accB[10], cB, v0);
            fma4(accB[11], cB, p1);
            fma4(accB[12], cB, p2);
        }
    }

    int pixA = b * PLANE + (y0 + 2 * r) * W + x;
    int pixB = pixA + W;
    atomicAdd(&normsq[pixA], accA[0]);
    atomicAdd(&normsq[pixB], accB[0]);
#pragma unroll
    for (int i = 0; i < NSHIFT; ++i) {
        atomicAdd(&dots[i * NPIX + pixA], accA[i + 1]);
        atomicAdd(&dots[i * NPIX + pixB], accB[i + 1]);
    }
}

// ---------------------------------------------------------------------------
// Kernel L: per-valid-pixel loss assembly (factor computed inline) + reduce
// ---------------------------------------------------------------------------
__global__ __launch_bounds__(256) void k_loss(const float* __restrict__ dots,
                                              const float* __restrict__ normsq,
                                              const int* __restrict__ seg,
                                              const int* __restrict__ gtb,
                                              const int* __restrict__ cnt,
                                              const int* __restrict__ inc,
                                              float* __restrict__ out) {
    int idx = blockIdx.x * 256 + threadIdx.x;
    int b = idx >> 14;
    int rem = idx & (PLANE - 1);
    int y = rem >> 7;
    int x = rem & 127;

    // factor[b] = inc_b ? 1/(24 * max(cnt_b,1) * scale_num) : 0   (uniform per block)
    int sn = 0;
#pragma unroll
    for (int b2 = 0; b2 < BATCH; b2++) sn += (inc[b2] != 0);
    if (sn < 1) sn = 1;
    int cb = cnt[b]; if (cb < 1) cb = 1;
    float factor = inc[b] ? 1.0f / (24.0f * (float)cb * (float)sn) : 0.0f;

    float val = 0.0f;
    if (y >= 2 && y < H - 2 && x >= 2 && x < W - 2) {
        int sp = seg[idx];
        int gp = gtb[idx];
        int s0 = (sp == 255) ? 0 : sp;
        int g0 = (gp == 255) ? 0 : gp;
        if (s0 > 0 && g0 > 0) {
            float np = fmaxf(sqrtf(normsq[idx]), 1e-8f);
            float sum = 0.0f;
#pragma unroll
            for (int i = 0; i < NSHIFT; ++i) {
                int off = S_DY[i] * W + S_DX[i];
                // + shift: cos(p, p+d)
                {
                    float d  = dots[i * NPIX + idx];
                    float nn = fmaxf(sqrtf(normsq[idx + off]), 1e-8f);
                    float cosv = d / (np * nn);
                    int sq = seg[idx + off];
                    float lab = (sp == sq && sp < 2) ? 1.0f : 0.0f;
                    float tt = cosv - lab;
                    sum = fmaf(tt, tt, sum);
                }
                // - shift: cos(p, p-d) = dot_d(p-d)/(norm(p)norm(p-d))
                {
                    float d  = dots[i * NPIX + idx - off];
                    float nn = fmaxf(sqrtf(normsq[idx - off]), 1e-8f);
                    float cosv = d / (np * nn);
                    int sq = seg[idx - off];
                    float lab = (sp == sq && sp < 2) ? 1.0f : 0.0f;
                    float tt = cosv - lab;
                    sum = fmaf(tt, tt, sum);
                }
            }
            val = sum * factor;
        }
    }

    // block reduction: wave shuffle then LDS across 4 waves
    for (int o = 32; o > 0; o >>= 1)
        val += __shfl_down(val, o, 64);
    __shared__ float wsum[4];
    int lane = threadIdx.x & 63;
    int wid  = threadIdx.x >> 6;
    if (lane == 0) wsum[wid] = val;
    __syncthreads();
    if (threadIdx.x == 0) {
        float s = wsum[0] + wsum[1] + wsum[2] + wsum[3];
        atomicAdd(out, s);
    }
}

// ---------------------------------------------------------------------------
extern "C" void kernel_launch(void* const* d_in, const int* in_sizes, int n_in,
                              void* d_out, int out_size, void* d_ws, size_t ws_size,
                              hipStream_t stream) {
    const float* er  = (const float*)d_in[0];
    const int*   seg = (const int*)d_in[1];
    const int*   gtb = (const int*)d_in[2];
    float* out = (float*)d_out;

    float* ws     = (float*)d_ws;
    float* dots   = ws;                      // 12 * NPIX floats (6.3 MB)
    float* normsq = dots + NSHIFT * NPIX;    // NPIX floats (512 KB)
    int*   cnt    = (int*)(normsq + NPIX);   // 8 ints
    int*   inc    = cnt + 8;                 // 8 ints

    hipLaunchKernelGGL(k_prep, dim3(NZB), dim3(256), 0, stream, (float4*)d_ws, out);
    hipLaunchKernelGGL(k_corr, dim3(NCORRB + NSTATB), dim3(256), 0, stream,
                       er, seg, gtb, dots, normsq, cnt, inc);
    hipLaunchKernelGGL(k_loss, dim3(NPIX / 256), dim3(256), 0, stream,
                       dots, normsq, seg, gtb, cnt, inc, out);
}

// Round 4
// 221.861 us; speedup vs baseline: 1.3027x; 1.0384x over previous
//
#include <hip/hip_runtime.h>
#include <math.h>

// Problem constants (fixed by setup_inputs)
#define BATCH 8
#define CH    256
#define H     128
#define W     128
#define PLANE (H * W)            // 16384
#define NPIX  (BATCH * PLANE)    // 131072
#define NSHIFT 12                // symmetric half of the 24 shifts
#define NMAPS  13                // 12 shifted dots + normsq
#define NCHUNK 8                 // channel chunks (8 co-resident blocks/CU)
#define CPC    (CH / NCHUNK)     // channels per chunk = 32
#define SLICE  (NMAPS * NPIX)    // floats per chunk slice

// 12 "positive" shifts: dy>0 or (dy==0 && dx>0). Negatives recovered by symmetry.
static __device__ __constant__ int S_DY[NSHIFT] = {0,0,1,1,1,1,1,2,2,2,2,2};
static __device__ __constant__ int S_DX[NSHIFT] = {1,2,-2,-1,0,1,2,-2,-1,0,1,2};

#define NCORRB (BATCH * 32 * NCHUNK)             // 2048 corr blocks
#define NSTATB (BATCH * 64)                      // 512 stats blocks

__device__ __forceinline__ void fma4(float& acc, const float4& a, const float4& b) {
    acc = fmaf(a.x, b.x, acc);
    acc = fmaf(a.y, b.y, acc);
    acc = fmaf(a.z, b.z, acc);
    acc = fmaf(a.w, b.w, acc);
}

// ---------------------------------------------------------------------------
// Kernel P: zero cnt/inc/out (slices need no init — every element is stored)
// ---------------------------------------------------------------------------
__global__ void k_prep(int* __restrict__ cnt, int* __restrict__ inc,
                       float* __restrict__ out) {
    int t = threadIdx.x;
    if (t < 8) { cnt[t] = 0; inc[t] = 0; }
    if (t == 0) out[0] = 0.0f;
}

// ---------------------------------------------------------------------------
// Kernel C: fused correlation + per-image stats.
// Blocks [0, NCORRB): correlation. Grid decode: chunk(8) | tile(32) | b(8).
//   256 thr; each thread computes 2 adjacent output rows (block covers 4
//   rows, stages 6 rows x 4 channels as float4-per-pixel in LDS).
//   Register-prefetch pipeline: next quad's 12 global loads issue during the
//   current quad's compute phase, consumed at the next ds_write.
//   Plain (non-atomic) stores into this chunk's private slice.
// Blocks [NCORRB, NCORRB+NSTATB): per-image cnt/inc stats.
// ---------------------------------------------------------------------------
__global__ __launch_bounds__(256) void k_corr(const float* __restrict__ er,
                                              const int* __restrict__ seg,
                                              const int* __restrict__ gtb,
                                              float* __restrict__ slices,
                                              int* __restrict__ cnt,
                                              int* __restrict__ inc) {
    __shared__ float4 lds[6][132];   // 6 staged rows, x padded by 2 each side
    int t = threadIdx.x;

    if (blockIdx.x >= NCORRB) {
        // ---- stats path ----
        int blk2 = blockIdx.x - NCORRB;
        int b = blk2 >> 6;
        int i = (blk2 & 63) * 256 + t;
        int my_cnt = 0, my_any = 0;
        {
            int s = seg[b * PLANE + i];
            int g = gtb[b * PLANE + i];
            int s0 = (s == 255) ? 0 : s;
            int g0 = (g == 255) ? 0 : g;
            if (s0 > 0 && g0 > 0) {
                my_any = 1;
                int y = i >> 7, x = i & 127;
                if (y >= 2 && y < H - 2 && x >= 2 && x < W - 2) my_cnt = 1;
            }
        }
        for (int o = 32; o > 0; o >>= 1) {
            my_cnt += __shfl_down(my_cnt, o, 64);
            my_any |= __shfl_down(my_any, o, 64);
        }
        __shared__ int sc[4], sa[4];
        int lane = t & 63, wid = t >> 6;
        if (lane == 0) { sc[wid] = my_cnt; sa[wid] = my_any; }
        __syncthreads();
        if (t == 0) {
            int c = sc[0] + sc[1] + sc[2] + sc[3];
            int a = sa[0] | sa[1] | sa[2] | sa[3];
            if (c) atomicAdd(&cnt[b], c);
            if (a) atomicOr(&inc[b], 1);
        }
        return;
    }

    // ---- correlation path ----
    int blk = blockIdx.x;
    int chunk = blk & 7;
    int tile  = (blk >> 3) & 31;
    int b     = blk >> 8;
    int y0 = tile * 4;               // block covers output rows y0..y0+3
    int c0 = chunk * CPC;
    int r = t >> 7;                  // thread handles output rows y0+2r, y0+2r+1
    int x = t & 127;

    // zero the x-pad slots once (first in-loop barrier makes them visible)
    if (t < 24) {
        int row = t >> 2, col = t & 3;
        int xs = (col < 2) ? col : (col + 128);   // 0,1,130,131
        lds[row][xs] = make_float4(0.f, 0.f, 0.f, 0.f);
    }

    float accA[13], accB[13];
#pragma unroll
    for (int i = 0; i < 13; i++) { accA[i] = 0.0f; accB[i] = 0.0f; }

    const float* base = er + (size_t)b * CH * PLANE;

    // prefetch registers: 3 stage slots x 4 channels
    float pf[3][4];
    auto load_quad = [&](int c) {
#pragma unroll
        for (int k = 0; k < 3; ++k) {
            int s = t + k * 256;         // 0..767
            int row = s >> 7;            // 0..5
            int xs = s & 127;
            int y = y0 + row;
            if (y < H) {
                const float* p0 = base + (size_t)c * PLANE + y * W + xs;
                pf[k][0] = p0[0];
                pf[k][1] = p0[PLANE];
                pf[k][2] = p0[2 * PLANE];
                pf[k][3] = p0[3 * PLANE];
            } else {
                pf[k][0] = 0.f; pf[k][1] = 0.f; pf[k][2] = 0.f; pf[k][3] = 0.f;
            }
        }
    };

    load_quad(c0);
    const int iters = CPC / 4;       // 8
    for (int it = 0; it < iters; ++it) {
        __syncthreads();   // prior iter's LDS reads done
        // commit prefetched quad to LDS (vmcnt wait lands here, after overlap)
#pragma unroll
        for (int k = 0; k < 3; ++k) {
            int s = t + k * 256;
            int row = s >> 7;
            int xs = s & 127;
            lds[row][xs + 2] = make_float4(pf[k][0], pf[k][1], pf[k][2], pf[k][3]);
        }
        __syncthreads();
        if (it + 1 < iters) load_quad(c0 + 4 * (it + 1));   // overlaps compute below

        const float4* lp = &lds[2 * r][x + 2];
        float4 cA = lp[0];               // (rel row 0, dx 0)
        float4 cB = lp[132];             // (rel row 1, dx 0)
        // rel row 0: dx {0,1,2} -> accA[0..2]
        {
            float4 v1 = lp[1], v2 = lp[2];
            fma4(accA[0], cA, cA);
            fma4(accA[1], cA, v1);
            fma4(accA[2], cA, v2);
        }
        // rel row 1: dx {-2..2} -> accA[3..7]; accB[0..2] (dx 0,1,2)
        {
            float4 m2 = lp[130], m1 = lp[131], p1 = lp[133], p2 = lp[134];
            fma4(accA[3], cA, m2);
            fma4(accA[4], cA, m1);
            fma4(accA[5], cA, cB);
            fma4(accA[6], cA, p1);
            fma4(accA[7], cA, p2);
            fma4(accB[0], cB, cB);
            fma4(accB[1], cB, p1);
            fma4(accB[2], cB, p2);
        }
        // rel row 2: dx {-2..2} -> accA[8..12]; accB[3..7]
        {
            float4 m2 = lp[262], m1 = lp[263], v0 = lp[264], p1 = lp[265], p2 = lp[266];
            fma4(accA[8],  cA, m2);
            fma4(accA[9],  cA, m1);
            fma4(accA[10], cA, v0);
            fma4(accA[11], cA, p1);
            fma4(accA[12], cA, p2);
            fma4(accB[3], cB, m2);
            fma4(accB[4], cB, m1);
            fma4(accB[5], cB, v0);
            fma4(accB[6], cB, p1);
            fma4(accB[7], cB, p2);
        }
        // rel row 3: dx {-2..2} -> accB[8..12]
        {
            float4 m2 = lp[394], m1 = lp[395], v0 = lp[396], p1 = lp[397], p2 = lp[398];
            fma4(accB[8],  cB, m2);
            fma4(accB[9],  cB, m1);
            fma4(accB[10], cB, v0);
            fma4(accB[11], cB, p1);
            fma4(accB[12], cB, p2);
        }
    }

    // plain coalesced stores into this chunk's private slice
    float* sp = slices + (size_t)chunk * SLICE;
    int pixA = b * PLANE + (y0 + 2 * r) * W + x;
    int pixB = pixA + W;
#pragma unroll
    for (int m = 0; m < NSHIFT; ++m) {
        sp[m * NPIX + pixA] = accA[m + 1];
        sp[m * NPIX + pixB] = accB[m + 1];
    }
    sp[NSHIFT * NPIX + pixA] = accA[0];
    sp[NSHIFT * NPIX + pixB] = accB[0];
}

// ---------------------------------------------------------------------------
// Kernel R: reduce the 8 chunk slices into the combined maps (float4 wide)
// ---------------------------------------------------------------------------
__global__ __launch_bounds__(256) void k_combine(const float4* __restrict__ sl,
                                                 float4* __restrict__ comb) {
    int i = blockIdx.x * 256 + threadIdx.x;     // over SLICE/4 elements (exact)
    float4 s = sl[i];
#pragma unroll
    for (int c = 1; c < NCHUNK; ++c) {
        float4 v = sl[(size_t)c * (SLICE / 4) + i];
        s.x += v.x; s.y += v.y; s.z += v.z; s.w += v.w;
    }
    comb[i] = s;
}

// ---------------------------------------------------------------------------
// Kernel L: per-valid-pixel loss assembly (factor computed inline) + reduce
// comb layout: maps 0..11 = shifted dots, map 12 = normsq
// ---------------------------------------------------------------------------
__global__ __launch_bounds__(256) void k_loss(const float* __restrict__ comb,
                                              const int* __restrict__ seg,
                                              const int* __restrict__ gtb,
                                              const int* __restrict__ cnt,
                                              const int* __restrict__ inc,
                                              float* __restrict__ out) {
    const float* dots   = comb;
    const float* normsq = comb + NSHIFT * NPIX;
    int idx = blockIdx.x * 256 + threadIdx.x;
    int b = idx >> 14;
    int rem = idx & (PLANE - 1);
    int y = rem >> 7;
    int x = rem & 127;

    // factor = inc_b ? 1/(24 * max(cnt_b,1) * scale_num) : 0  (uniform per block)
    int sn = 0;
#pragma unroll
    for (int b2 = 0; b2 < BATCH; b2++) sn += (inc[b2] != 0);
    if (sn < 1) sn = 1;
    int cb = cnt[b]; if (cb < 1) cb = 1;
    float factor = inc[b] ? 1.0f / (24.0f * (float)cb * (float)sn) : 0.0f;

    float val = 0.0f;
    if (y >= 2 && y < H - 2 && x >= 2 && x < W - 2) {
        int sp = seg[idx];
        int gp = gtb[idx];
        int s0 = (sp == 255) ? 0 : sp;
        int g0 = (gp == 255) ? 0 : gp;
        if (s0 > 0 && g0 > 0) {
            float np = fmaxf(sqrtf(normsq[idx]), 1e-8f);
            float sum = 0.0f;
#pragma unroll
            for (int i = 0; i < NSHIFT; ++i) {
                int off = S_DY[i] * W + S_DX[i];
                // + shift: cos(p, p+d)
                {
                    float d  = dots[i * NPIX + idx];
                    float nn = fmaxf(sqrtf(normsq[idx + off]), 1e-8f);
                    float cosv = d / (np * nn);
                    int sq = seg[idx + off];
                    float lab = (sp == sq && sp < 2) ? 1.0f : 0.0f;
                    float tt = cosv - lab;
                    sum = fmaf(tt, tt, sum);
                }
                // - shift: cos(p, p-d) = dot_d(p-d)/(norm(p)norm(p-d))
                {
                    float d  = dots[i * NPIX + idx - off];
                    float nn = fmaxf(sqrtf(normsq[idx - off]), 1e-8f);
                    float cosv = d / (np * nn);
                    int sq = seg[idx - off];
                    float lab = (sp == sq && sp < 2) ? 1.0f : 0.0f;
                    float tt = cosv - lab;
                    sum = fmaf(tt, tt, sum);
                }
            }
            val = sum * factor;
        }
    }

    // block reduction: wave shuffle then LDS across 4 waves
    for (int o = 32; o > 0; o >>= 1)
        val += __shfl_down(val, o, 64);
    __shared__ float wsum[4];
    int lane = threadIdx.x & 63;
    int wid  = threadIdx.x >> 6;
    if (lane == 0) wsum[wid] = val;
    __syncthreads();
    if (threadIdx.x == 0) {
        float s = wsum[0] + wsum[1] + wsum[2] + wsum[3];
        atomicAdd(out, s);
    }
}

// ---------------------------------------------------------------------------
extern "C" void kernel_launch(void* const* d_in, const int* in_sizes, int n_in,
                              void* d_out, int out_size, void* d_ws, size_t ws_size,
                              hipStream_t stream) {
    const float* er  = (const float*)d_in[0];
    const int*   seg = (const int*)d_in[1];
    const int*   gtb = (const int*)d_in[2];
    float* out = (float*)d_out;

    float* ws     = (float*)d_ws;
    float* comb   = ws;                          // 13 * NPIX floats (6.8 MB)
    float* slices = comb + SLICE;                // 8 * 13 * NPIX floats (54.5 MB)
    int*   cnt    = (int*)(slices + (size_t)NCHUNK * SLICE);   // 8 ints
    int*   inc    = cnt + 8;                     // 8 ints

    hipLaunchKernelGGL(k_prep,    dim3(1), dim3(64), 0, stream, cnt, inc, out);
    hipLaunchKernelGGL(k_corr,    dim3(NCORRB + NSTATB), dim3(256), 0, stream,
                       er, seg, gtb, slices, cnt, inc);
    hipLaunchKernelGGL(k_combine, dim3(SLICE / 4 / 256), dim3(256), 0, stream,
                       (const float4*)slices, (float4*)comb);
    hipLaunchKernelGGL(k_loss,    dim3(NPIX / 256), dim3(256), 0, stream,
                       comb, seg, gtb, cnt, inc, out);
}